// Round 1
// baseline (276.307 us; speedup 1.0000x reference)
//
#include <hip/hip_runtime.h>

#define NBLOCKS 2048
#define NTHREADS 256

__global__ __launch_bounds__(NTHREADS) void loss1_partial(
    const float* __restrict__ x, const float* __restrict__ y,
    long long n, float* __restrict__ psum, int* __restrict__ pcnt) {
    long long tid = (long long)blockIdx.x * blockDim.x + threadIdx.x;
    long long stride = (long long)gridDim.x * blockDim.x;
    long long nvec = n >> 2;  // n is 32*1024*1024, divisible by 4

    const float4* __restrict__ x4 = (const float4*)x;
    const float4* __restrict__ y4 = (const float4*)y;

    float s = 0.0f;
    int c = 0;
    for (long long i = tid; i < nvec; i += stride) {
        float4 a = x4[i];
        float4 b = y4[i];
        float d0 = a.x - b.x;
        float d1 = a.y - b.y;
        float d2 = a.z - b.z;
        float d3 = a.w - b.w;
        // mask is x > y  <=>  d > 0 (inputs are finite normals)
        s += (a.x > b.x) ? d0 : 0.0f;  c += (a.x > b.x);
        s += (a.y > b.y) ? d1 : 0.0f;  c += (a.y > b.y);
        s += (a.z > b.z) ? d2 : 0.0f;  c += (a.z > b.z);
        s += (a.w > b.w) ? d3 : 0.0f;  c += (a.w > b.w);
    }
    // scalar tail (none for this shape, but keep correct in general)
    if (tid == 0) {
        for (long long i = nvec << 2; i < n; ++i) {
            float d = x[i] - y[i];
            if (x[i] > y[i]) { s += d; c += 1; }
        }
    }

    // wave-64 shuffle reduction
    #pragma unroll
    for (int off = 32; off > 0; off >>= 1) {
        s += __shfl_down(s, off, 64);
        c += __shfl_down(c, off, 64);
    }

    __shared__ float ss[NTHREADS / 64];
    __shared__ int   sc[NTHREADS / 64];
    int lane = threadIdx.x & 63;
    int wave = threadIdx.x >> 6;
    if (lane == 0) { ss[wave] = s; sc[wave] = c; }
    __syncthreads();
    if (threadIdx.x == 0) {
        float ts = 0.0f; int tc = 0;
        #pragma unroll
        for (int w = 0; w < NTHREADS / 64; ++w) { ts += ss[w]; tc += sc[w]; }
        psum[blockIdx.x] = ts;
        pcnt[blockIdx.x] = tc;
    }
}

__global__ __launch_bounds__(1024) void loss1_final(
    const float* __restrict__ psum, const int* __restrict__ pcnt,
    int nparts, float* __restrict__ out) {
    int tid = threadIdx.x;
    float s = 0.0f;
    int c = 0;
    for (int i = tid; i < nparts; i += 1024) {
        s += psum[i];
        c += pcnt[i];
    }
    #pragma unroll
    for (int off = 32; off > 0; off >>= 1) {
        s += __shfl_down(s, off, 64);
        c += __shfl_down(c, off, 64);
    }
    __shared__ float ss[16];
    __shared__ int   sc[16];
    int lane = tid & 63;
    int wave = tid >> 6;
    if (lane == 0) { ss[wave] = s; sc[wave] = c; }
    __syncthreads();
    if (tid == 0) {
        float ts = 0.0f; int tc = 0;
        #pragma unroll
        for (int w = 0; w < 16; ++w) { ts += ss[w]; tc += sc[w]; }
        out[0] = (tc > 0) ? (ts / (float)tc) : 0.0f;
    }
}

extern "C" void kernel_launch(void* const* d_in, const int* in_sizes, int n_in,
                              void* d_out, int out_size, void* d_ws, size_t ws_size,
                              hipStream_t stream) {
    const float* x = (const float*)d_in[0];
    const float* y = (const float*)d_in[1];
    long long n = (long long)in_sizes[0];

    float* psum = (float*)d_ws;
    int*   pcnt = (int*)((char*)d_ws + NBLOCKS * sizeof(float));

    loss1_partial<<<NBLOCKS, NTHREADS, 0, stream>>>(x, y, n, psum, pcnt);
    loss1_final<<<1, 1024, 0, stream>>>(psum, pcnt, NBLOCKS, (float*)d_out);
}